// Round 6
// baseline (68.718 us; speedup 1.0000x reference)
//
#include <hip/hip_runtime.h>
#include <hip/hip_bf16.h>
#include <stdint.h>

typedef unsigned short u16;
typedef __attribute__((ext_vector_type(8))) unsigned short u16x8;
typedef __attribute__((ext_vector_type(8))) __bf16 bf16x8;
typedef __attribute__((ext_vector_type(4))) float f32x4;

__device__ __forceinline__ u16 f2bf(float f) {
    uint32_t u = __builtin_bit_cast(uint32_t, f);
    u = (u + 0x7fffu + ((u >> 16) & 1u)) >> 16;
    return (u16)u;
}

__device__ __forceinline__ bf16x8 cvt8(const float* p) {
    f32x4 a = *(const f32x4*)p;
    f32x4 b = *(const f32x4*)(p + 4);
    u16x8 o;
    o[0] = f2bf(a[0]); o[1] = f2bf(a[1]); o[2] = f2bf(a[2]); o[3] = f2bf(a[3]);
    o[4] = f2bf(b[0]); o[5] = f2bf(b[1]); o[6] = f2bf(b[2]); o[7] = f2bf(b[3]);
    return __builtin_bit_cast(bf16x8, o);
}

// ---------------- H12bT[p*64+e][k=i1*32+j2] = bf16((G1 G2-slice)[a][b]), i2=2*j2+p, e=a*8+b
// One thread per OUTPUT element -> coalesced u16 writes; f0/f1 are 16 KB (L1-hot).
__global__ __launch_bounds__(256) void h12b_kernel(const float* __restrict__ f0,
                                                   const float* __restrict__ f1,
                                                   u16* __restrict__ H12bT) {
    int idx = blockIdx.x * 256 + threadIdx.x;       // 262144 = [128][2048]
    int rc = idx >> 11;                              // p*64 + e
    int k  = idx & 2047;                             // i1*32 + j2
    int p = rc >> 6, e = rc & 63;
    int a = e >> 3, b = e & 7;
    int i1 = k >> 5, i2 = ((k & 31) << 1) | p;
    float s = 0.f;
#pragma unroll
    for (int m = 0; m < 8; m++)
        s += f0[a * 512 + i1 * 8 + m] * f1[m * 512 + i2 * 8 + b];
    H12bT[idx] = f2bf(s);
}

// ---------------- H34T[c][e=a*8+b] = (M3M4)[b][a], c=i3*16+i4   (bf16, [1024][64])
__global__ __launch_bounds__(256) void h34t_kernel(const float* __restrict__ f2,
                                                   const float* __restrict__ f3,
                                                   u16* __restrict__ H34T) {
    int gid = blockIdx.x * 256 + threadIdx.x;       // 65536
    int c = gid >> 6;
    int e = gid & 63;
    int a = e >> 3, b = e & 7;
    int i3 = c >> 4, i4 = c & 15;
    float s = 0.f;
#pragma unroll
    for (int cc = 0; cc < 8; cc++)
        s += f2[b * 512 + i3 * 8 + cc] * f3[cc * 128 + i4 * 8 + a];
    H34T[c * 64 + e] = f2bf(s);
}

// ---------------- Fused: per block, 16 rows of x -> Y(16x128) in LDS -> out(16x2048)
// Stage 1: wave w handles K in [w*512,(w+1)*512); f32 partials to LDS; reduce; bf16 Y.
// Stage 2: wave w handles out cols [w*512,(w+1)*512); B = H34T (L2-resident).
__global__ __launch_bounds__(256, 2) void fused_kernel(const float* __restrict__ x,
                                                       const u16* __restrict__ H12bT,
                                                       const u16* __restrict__ H34T,
                                                       float* __restrict__ out) {
    __shared__ float Lr[4][16][132];   // 33 KB, padded: writes 2-way, reads 4-way
    __shared__ u16 Yl[16][136];        // 4.25 KB bf16 Y tile, padded

    int tid = threadIdx.x, lane = tid & 63, w = tid >> 6;
    int lm = lane & 15, lkE = (lane >> 4) << 3;
    int r0 = blockIdx.x * 16;

    // ---- stage 1
    f32x4 acc[8];
#pragma unroll
    for (int j = 0; j < 8; ++j) acc[j] = (f32x4){0.f, 0.f, 0.f, 0.f};

    const float* xA = x + (size_t)(r0 + lm) * 2048 + (w << 9) + lkE;
    const u16*   bP = H12bT + (size_t)lm * 2048 + (w << 9) + lkE;

#pragma unroll 2
    for (int kc = 0; kc < 16; ++kc) {
        int ko = kc * 32;
        bf16x8 a0 = cvt8(xA + ko);
        bf16x8 bf[8];
#pragma unroll
        for (int j = 0; j < 8; ++j)
            bf[j] = __builtin_bit_cast(bf16x8, *(const u16x8*)(bP + (size_t)j * 32768 + ko));
#pragma unroll
        for (int j = 0; j < 8; ++j)
            acc[j] = __builtin_amdgcn_mfma_f32_16x16x32_bf16(a0, bf[j], acc[j], 0, 0, 0);
    }
    // partials -> LDS: row = (lane>>4)*4+r, col = j*16+lm  (C/D layout verified r1-r5)
#pragma unroll
    for (int j = 0; j < 8; ++j)
#pragma unroll
        for (int r = 0; r < 4; ++r)
            Lr[w][((lane >> 4) << 2) + r][j * 16 + lm] = acc[j][r];
    __syncthreads();

    // ---- reduce across waves, convert to bf16
    {
        int row = tid >> 4, c0 = (tid & 15) << 3;
        f32x4 sa = (f32x4){0.f, 0.f, 0.f, 0.f}, sb = sa;
#pragma unroll
        for (int ww = 0; ww < 4; ++ww) {
            sa += *(const f32x4*)&Lr[ww][row][c0];
            sb += *(const f32x4*)&Lr[ww][row][c0 + 4];
        }
        u16x8 o;
        o[0] = f2bf(sa[0]); o[1] = f2bf(sa[1]); o[2] = f2bf(sa[2]); o[3] = f2bf(sa[3]);
        o[4] = f2bf(sb[0]); o[5] = f2bf(sb[1]); o[6] = f2bf(sb[2]); o[7] = f2bf(sb[3]);
        *(u16x8*)&Yl[row][c0] = o;
    }
    __syncthreads();

    // ---- stage 2: out[r0..r0+15][w*512 .. w*512+511]
    // col n = w*512 + cf*16 + lm ; p = n>>10 = w>>1 ; c = n&1023 = (w&1)*512 + cf*16 + lm
    int p = w >> 1, ch = (w & 1) << 9;
    bf16x8 ya0 = __builtin_bit_cast(bf16x8, *(const u16x8*)&Yl[lm][p * 64 + lkE]);
    bf16x8 ya1 = __builtin_bit_cast(bf16x8, *(const u16x8*)&Yl[lm][p * 64 + 32 + lkE]);
    const u16* hB = H34T + (size_t)(ch + lm) * 64 + lkE;
    float* cW = out + (size_t)(r0 + ((lane >> 4) << 2)) * 2048 + (w << 9) + lm;

#pragma unroll 4
    for (int cf = 0; cf < 32; ++cf) {
        const u16* hr = hB + (size_t)cf * 1024;     // 16 rows * 64
        bf16x8 h0 = __builtin_bit_cast(bf16x8, *(const u16x8*)(hr));
        bf16x8 h1 = __builtin_bit_cast(bf16x8, *(const u16x8*)(hr + 32));
        f32x4 a2 = (f32x4){0.f, 0.f, 0.f, 0.f};
        a2 = __builtin_amdgcn_mfma_f32_16x16x32_bf16(ya0, h0, a2, 0, 0, 0);
        a2 = __builtin_amdgcn_mfma_f32_16x16x32_bf16(ya1, h1, a2, 0, 0, 0);
#pragma unroll
        for (int r = 0; r < 4; ++r)
            cW[(size_t)r * 2048 + cf * 16] = a2[r];
    }
}

extern "C" void kernel_launch(void* const* d_in, const int* in_sizes, int n_in,
                              void* d_out, int out_size, void* d_ws, size_t ws_size,
                              hipStream_t stream) {
    const float* x  = (const float*)d_in[0];
    const float* f0 = (const float*)d_in[1];
    const float* f1 = (const float*)d_in[2];
    const float* f2 = (const float*)d_in[3];
    const float* f3 = (const float*)d_in[4];
    float* out = (float*)d_out;

    char* ws = (char*)d_ws;
    u16* H12bT = (u16*)ws;                    // 512 KB [128][2048] bf16
    u16* H34T  = (u16*)(ws + (512u << 10));   // 128 KB [1024][64] bf16
    if (ws_size < ((size_t)1 << 20)) return;

    h12b_kernel<<<1024, 256, 0, stream>>>(f0, f1, H12bT);
    h34t_kernel<<<256, 256, 0, stream>>>(f2, f3, H34T);
    fused_kernel<<<512, 256, 0, stream>>>(x, H12bT, H34T, out);
}